// Round 14
// baseline (110.769 us; speedup 1.0000x reference)
//
#include <hip/hip_runtime.h>

// Depthwise 3x3 conv, NHWC, stride 1, SAME, fp32.
// x: (32,112,112,192), w: (3,3,1,192), b: (192), out: (32,112,112,192)
//
// R14: channel-COMPLETE dense streams. Block = 192 thr = 4w x 48c4 (all
//      channels of its pixels): reads = full 768-B pixel spans, writes =
//      3-KB contiguous runs (every prior kernel channel-split 1/3-1/6 ->
//      strided partial bursts; testing DRAM-efficiency theory for the
//      107us plateau). Machinery = champion R6/R9: LDS ring of 4 two-row
//      slabs (2 x 6cols x 48c4 = 9216 B; 36.9 KB -> 4 blocks/CU), one
//      barrier/tile [vmcnt -> barrier -> stage 2 rows (3 chunks/wave,
//      uniform) -> consume -> NT store], counted vmcnt {3,5,7..7,4}.

constexpr int Bn = 32, Hn = 112, Wn = 112, Cn = 192, C4 = 48;
constexpr int WT = 4;                  // output cols per block
constexpr int WTiles = Wn / WT;        // 28
constexpr int NSTEP = 14, HG = 4;      // 28 output rows per block
constexpr int LWC = 6;                 // staged cols (4 + 2 halo)
constexpr int ROWF4 = LWC * C4;        // 288 f4 = 4608 B per staged row
constexpr int SLABF4 = 2 * ROWF4;      // 2-row slab = 576 f4 = 9 chunks
constexpr int SLABB = SLABF4 * 16;     // 9216 B
constexpr int NSLOT = 4;               // ring slabs; 36,864 B LDS

typedef float floatx4 __attribute__((ext_vector_type(4)));

#define VMWAIT(n) asm volatile("s_waitcnt vmcnt(" #n ")" ::: "memory")

__device__ __forceinline__ floatx4 fma4(floatx4 a, floatx4 b, floatx4 c) {
  c.x = fmaf(a.x, b.x, c.x);
  c.y = fmaf(a.y, b.y, c.y);
  c.z = fmaf(a.z, b.z, c.z);
  c.w = fmaf(a.w, b.w, c.w);
  return c;
}

__global__ __launch_bounds__(192, 4) void dwconv3x3_dense(
    const float* __restrict__ x,
    const float* __restrict__ wgt,   // (3,3,1,192)
    const float* __restrict__ bias,  // (192)
    float* __restrict__ out) {
  __shared__ char lds[NSLOT * SLABB];  // 36,864 B
  const int tid = (int)threadIdx.x;
  const int lane = tid & 63;
  const int wave = tid >> 6;  // 0..2

  // Chunked XCD swizzle (3584 % 8 == 0): w-neighbors (halo overlap) and
  // h-neighbors share one XCD L2.
  int bid = blockIdx.x;
  int chk = gridDim.x >> 3;  // 448
  int sbid = (bid & 7) * chk + (bid >> 3);
  int wt = sbid % WTiles; int tt = sbid / WTiles;
  int hg = tt & 3;        int b = tt >> 2;

  const int hbase = hg * (2 * NSTEP);
  const int w0 = wt * WT;
  const float* xb = x + (long)b * Hn * Wn * Cn;
  const int rstr = Wn * Cn;

  // Slab = 2 rows x 6 cols x 48 c4, layout [row2][col][c4]. 9 chunks of
  // 1 KB; wave w owns chunks 3w..3w+2. Per-chunk lane mapping (invariant).
  int rowadd[3], coloff[3];
#pragma unroll
  for (int j = 0; j < 3; ++j) {
    int q = (3 * wave + j) * 64 + lane;      // f4 linear in slab (0..575)
    rowadd[j] = q / ROWF4;                   // 0 or 1
    int rem = q % ROWF4;
    int col = rem / C4, c4l = rem % C4;
    int wc = min(max(w0 + col - 1, 0), Wn - 1);  // w-halo clamp (wv kills)
    coloff[j] = wc * Cn + c4l * 4;
  }

  // Stage 2-row group g (staged rows 2g, 2g+1; input h = hbase+row-1).
  auto stage = [&](int g) {
    char* slab = lds + (g & 3) * SLABB;
#pragma unroll
    for (int j = 0; j < 3; ++j) {
      int h = min(max(hbase + 2 * g + rowadd[j] - 1, 0), Hn - 1);
      const float* src = xb + (long)h * rstr + coloff[j];
      __builtin_amdgcn_global_load_lds(
          (const __attribute__((address_space(1))) void*)src,
          (__attribute__((address_space(3))) void*)(slab + (3 * wave + j) * 1024),
          16, 0, 0);
    }
  };

  // Prologue: groups 0..2 (staged rows 0..5; 9 chunks/wave).
  stage(0); stage(1); stage(2);

  // Weights (all 192 channels across the block; L1-broadcast) with w-edge
  // validity folded; bias.
  const int c4i = tid % C4;
  const int wi = tid / C4;             // 0..3
  const int cofs = c4i * 4;
  const int wg = w0 + wi;
  const float cs0 = (wg >= 1) ? 1.f : 0.f;
  const float cs2 = (wg <= Wn - 2) ? 1.f : 0.f;
  floatx4 wv[3][3];
#pragma unroll
  for (int kh = 0; kh < 3; ++kh) {
#pragma unroll
    for (int kw = 0; kw < 3; ++kw)
      wv[kh][kw] = *(const floatx4*)(wgt + (kh * 3 + kw) * Cn + cofs);
    wv[kh][0] *= cs0;
    wv[kh][2] *= cs2;
  }
  const floatx4 bv = *(const floatx4*)(bias + cofs);
  const float sTop = (hg == 0) ? 0.f : 1.f;       // staged row 0
  const float sBot = (hg == HG - 1) ? 0.f : 1.f;  // staged row 29

  const int ostr = Wn * C4;
  floatx4* outp = (floatx4*)out +
      ((long)(b * Hn + hbase) * Wn + wg) * C4 + c4i;
  // Consume base: col (wi+1), this c4, xv0/xv2 at -/+ 768 B.
  const int cbyte = (wi + 1) * (C4 * 16) + c4i * 16;

  // Tile t: consume staged rows 2t..2t+3 (groups t, t+1); stage group t+3
  // (t<=11). vmcnt (3 loads/group, 2 stores/tile): {3,5,7,...,7,4}.
#pragma unroll
  for (int t = 0; t < NSTEP; ++t) {
    if (t == 0)              VMWAIT(3);
    else if (t == 1)         VMWAIT(5);
    else if (t < NSTEP - 1)  VMWAIT(7);
    else                     VMWAIT(4);
    __builtin_amdgcn_s_barrier();

    // Stage group t+3 into slab (t+3)&3 == (t-1)&3: consumed at t-1, whose
    // ds_reads retired before barrier(t) (FMA use forces lgkmcnt drain).
    if (t <= NSTEP - 3) stage(t + 3);

    floatx4 acc[2] = {bv, bv};
    // Staged rows 2t+r, r=0..3: group t (r<2) / t+1 (r>=2), row2 = r&1.
#pragma unroll
    for (int r = 0; r < 4; ++r) {
      const int g = t + (r >> 1);
      const char* base = lds + (g & 3) * SLABB + (r & 1) * (ROWF4 * 16) + cbyte;
      floatx4 xv0 = *(const floatx4*)(base - 768);
      floatx4 xv1 = *(const floatx4*)(base);
      floatx4 xv2 = *(const floatx4*)(base + 768);
      if (t == 0 && r == 0) { xv0 *= sTop; xv1 *= sTop; xv2 *= sTop; }
      if (t == NSTEP - 1 && r == 3) { xv0 *= sBot; xv1 *= sBot; xv2 *= sBot; }
#pragma unroll
      for (int o = 0; o < 2; ++o) {
        int kh = r - o;
        if (kh >= 0 && kh < 3) {
          acc[o] = fma4(xv0, wv[kh][0], acc[o]);
          acc[o] = fma4(xv1, wv[kh][1], acc[o]);
          acc[o] = fma4(xv2, wv[kh][2], acc[o]);
        }
      }
    }

#pragma unroll
    for (int o = 0; o < 2; ++o)
      __builtin_nontemporal_store(acc[o], outp + (long)(2 * t + o) * ostr);
  }
}

extern "C" void kernel_launch(void* const* d_in, const int* in_sizes, int n_in,
                              void* d_out, int out_size, void* d_ws, size_t ws_size,
                              hipStream_t stream) {
  const float* x = (const float*)d_in[0];
  const float* w = (const float*)d_in[1];
  const float* b = (const float*)d_in[2];
  float* out = (float*)d_out;

  const int grid = Bn * HG * WTiles;  // 3584, divisible by 8
  dwconv3x3_dense<<<grid, 192, 0, stream>>>(x, w, b, out);
}